// Round 1
// baseline (9.583 us; speedup 1.0000x reference)
//
#include <hip/hip_runtime.h>
#include <hip/hip_bf16.h>

// CrowdCountingLoss: out = BETA*mean((pred-gt_blur)^2) + BETA*|pred_count-gt_count|
//                          (+ BETA*ALPHA*sinkhorn, which is input-independent and
//                           ~6e-40 * 2.88e-11 ~ 2e-50 -> underflows to 0 in f32)
//
// H*W = 4096 floats per map. One workgroup of 256 threads, float4 loads,
// wave64 shuffle reduce -> LDS -> thread 0 writes the scalar.

#define BETA_F 8e-05f
#define N_ELEM 4096

__global__ __launch_bounds__(256) void crowd_loss_kernel(
    const float* __restrict__ pred,
    const float* __restrict__ gt_blur,
    const float* __restrict__ pred_count,
    const float* __restrict__ gt_count,
    float* __restrict__ out)
{
    const int tid = threadIdx.x;           // 0..255
    __shared__ float sdata[4];             // one partial per wave64

    // Each thread processes 16 elements as 4x float4 (stride-256 float4s).
    const float4* p4 = reinterpret_cast<const float4*>(pred);
    const float4* g4 = reinterpret_cast<const float4*>(gt_blur);

    float sum = 0.0f;
#pragma unroll
    for (int k = 0; k < 4; ++k) {
        int idx = tid + k * 256;           // float4 index, 0..1023
        float4 a = p4[idx];
        float4 b = g4[idx];
        float d0 = a.x - b.x;
        float d1 = a.y - b.y;
        float d2 = a.z - b.z;
        float d3 = a.w - b.w;
        sum += d0 * d0 + d1 * d1 + d2 * d2 + d3 * d3;
    }

    // wave64 butterfly reduce
#pragma unroll
    for (int off = 32; off > 0; off >>= 1)
        sum += __shfl_down(sum, off, 64);

    const int wave = tid >> 6;
    if ((tid & 63) == 0) sdata[wave] = sum;
    __syncthreads();

    if (tid == 0) {
        float s = sdata[0] + sdata[1] + sdata[2] + sdata[3];
        float density = s * (1.0f / (float)N_ELEM);
        float count = fabsf(pred_count[0] - gt_count[0]);
        // Match reference association: BETA*density + BETA*count (+ 0 sinkhorn)
        out[0] = BETA_F * density + BETA_F * count;
    }
}

extern "C" void kernel_launch(void* const* d_in, const int* in_sizes, int n_in,
                              void* d_out, int out_size, void* d_ws, size_t ws_size,
                              hipStream_t stream) {
    const float* pred_map   = (const float*)d_in[0];
    // d_in[1] = gt_map: unused by the math (sinkhorn is value-independent)
    const float* gt_blur    = (const float*)d_in[2];
    const float* pred_count = (const float*)d_in[3];
    const float* gt_count   = (const float*)d_in[4];
    float* out = (float*)d_out;

    crowd_loss_kernel<<<1, 256, 0, stream>>>(pred_map, gt_blur, pred_count, gt_count, out);
}